// Round 2
// baseline (142.299 us; speedup 1.0000x reference)
//
#include <hip/hip_runtime.h>
#include <math.h>

// Problem constants (fixed by setup_inputs): C=64, HW=128*128, bins=256.
#define C_CH  64
#define HW    16384
#define BINS  256
#define NBLK  256          // 4 blocks per channel
#define QHW   4096         // elements per block (quarter channel)

// ---- ws layout (all cross-block cells accessed via device-scope atomics) ----
#define WS_HIST  0                      // 64*256 int combined histograms
#define WS_PMIN  (C_CH * BINS)          // 64*4 float partial min of match*mask
#define WS_PMAX  (WS_PMIN + C_CH * 4)   // 64*4 float partial max
#define WS_IPMN  (WS_PMAX + C_CH * 4)   // 4 float ch0 input*mask partial min
#define WS_IPMX  (WS_IPMN + 4)          // 4 float ch0 input*mask partial max
#define WS_MSUM  (WS_IPMX + 4)          // 4 float mask partial sums
#define WS_SSE   (WS_MSUM + 4)          // float SSE accumulator
#define WS_CNT   (WS_SSE + 1)           // int ticket counter

// Grid-barrier state: module-static device memory (zero-initialized at load,
// self-maintaining afterwards: gen grows monotonically, cnt returns to 0).
__device__ unsigned g_bar_cnt = 0;
__device__ unsigned g_bar_gen = 0;

__device__ inline float4 ld4(const float* p) { return *(const float4*)p; }
// Coherent (device-scope) loads: atomic RMW with identity — guaranteed to see
// other XCDs' atomics regardless of per-XCD L2 non-coherence.
__device__ inline float aldf(float* p) { return atomicAdd(p, 0.0f); }
__device__ inline int   aldi(int* p)   { return atomicAdd(p, 0); }

// Sense-reversing grid barrier. Safe: 256 blocks x 256 thr, ~7KB LDS, VGPR
// well under limits -> all blocks co-resident (capacity >= 256 CUs x 2+).
__device__ inline void gridbar() {
    __syncthreads();
    if (threadIdx.x == 0) {
        __threadfence();   // release: prior writes visible device-wide
        unsigned g = __hip_atomic_load(&g_bar_gen, __ATOMIC_RELAXED, __HIP_MEMORY_SCOPE_AGENT);
        if (atomicAdd(&g_bar_cnt, 1u) == NBLK - 1u) {
            atomicExch(&g_bar_cnt, 0u);   // reset BEFORE releasing waiters
            __threadfence();
            atomicAdd(&g_bar_gen, 1u);
        } else {
            while (__hip_atomic_load(&g_bar_gen, __ATOMIC_RELAXED, __HIP_MEMORY_SCOPE_AGENT) == g)
                __builtin_amdgcn_s_sleep(1);
        }
        __threadfence();   // acquire side
    }
    __syncthreads();
}

__device__ inline int lbound(const float* a, float rank) {
    int lo = 0, hi = BINS;
    while (lo < hi) { int mid = (lo + hi) >> 1; if (a[mid] < rank) lo = mid + 1; else hi = mid; }
    return (lo > 255) ? 255 : lo;   // defensive; a[255]=N>=rank
}

// One fused kernel, 256 blocks x 256 threads. Block (c=blk>>2, q=blk&3) owns
// quarter q of channel c. Phases:
//  A: load match/input/mask once -> regs; partial min/max; zero shared cells
//  B: combine channel min/max; LDS histogram from regs; combine to global
//  C+D: redundant per-block cdf scan (wave0=ch c, wave1=ch0), T LUT,
//       marching CDF inversion from regs, SSE reduce, ticket finale.
__global__ __launch_bounds__(256) void fused(const float* __restrict__ input,
                                             const float* __restrict__ match,
                                             const float* __restrict__ mask,
                                             float* __restrict__ ws,
                                             float* __restrict__ out) {
    const int blk = blockIdx.x, tid = threadIdx.x;
    const int c = blk >> 2, q = blk & 3, base = q * QHW;
    const int wave = tid >> 6, lane = tid & 63;
    int* iws = (int*)ws;

    __shared__ int   hist[BINS];
    __shared__ int   shc[BINS], sh0[BINS];
    __shared__ float scdf[BINS], sc0[BINS], sT[BINS];
    __shared__ float wr_a[4], wr_b[4], wr_c[4], wr_d[4], wr_e[4];
    __shared__ float s_mn, s_mx, s_xmn, s_xmx;

    // ---------------- phase A: all global loads, once ----------------
    const float* m  = match + c * HW + base;
    const float* x  = input + c * HW + base;
    const float* mk = mask + base;

    float vm[16], vx[16];
    float mn = INFINITY, mx = -INFINITY;
    float xmn = INFINITY, xmx = -INFINITY, msum = 0.0f;
    #pragma unroll
    for (int k = 0; k < 4; k++) {
        float4 mv = ld4(m  + k * 1024 + 4 * tid);
        float4 kv = ld4(mk + k * 1024 + 4 * tid);
        float4 xv = ld4(x  + k * 1024 + 4 * tid);
        vm[4*k+0] = mv.x * kv.x; vm[4*k+1] = mv.y * kv.y;
        vm[4*k+2] = mv.z * kv.z; vm[4*k+3] = mv.w * kv.w;
        vx[4*k+0] = xv.x * kv.x; vx[4*k+1] = xv.y * kv.y;
        vx[4*k+2] = xv.z * kv.z; vx[4*k+3] = xv.w * kv.w;
        #pragma unroll
        for (int j = 0; j < 4; j++) {
            mn = fminf(mn, vm[4*k+j]);
            mx = fmaxf(mx, vm[4*k+j]);
        }
        if (c == 0) {
            #pragma unroll
            for (int j = 0; j < 4; j++) {
                xmn = fminf(xmn, vx[4*k+j]);
                xmx = fmaxf(xmx, vx[4*k+j]);
            }
            msum += kv.x + kv.y + kv.z + kv.w;   // 0/1: exact
        }
    }
    #pragma unroll
    for (int s = 32; s > 0; s >>= 1) {
        mn = fminf(mn, __shfl_xor(mn, s, 64));
        mx = fmaxf(mx, __shfl_xor(mx, s, 64));
    }
    if (c == 0) {
        #pragma unroll
        for (int s = 32; s > 0; s >>= 1) {
            xmn = fminf(xmn, __shfl_xor(xmn, s, 64));
            xmx = fmaxf(xmx, __shfl_xor(xmx, s, 64));
            msum += __shfl_xor(msum, s, 64);
        }
    }
    if (lane == 0) {
        wr_a[wave] = mn; wr_b[wave] = mx;
        if (c == 0) { wr_c[wave] = msum; wr_d[wave] = xmn; wr_e[wave] = xmx; }
    }
    // zero shared global cells before barrier 1 (ws is poisoned each iter)
    if (q == 0) atomicExch(&iws[WS_HIST + c * BINS + tid], 0);
    if (blk == 0 && tid == 0) { atomicExch(&ws[WS_SSE], 0.0f); atomicExch(&iws[WS_CNT], 0); }
    __syncthreads();
    if (tid == 0) {
        float a = wr_a[0], b = wr_b[0];
        #pragma unroll
        for (int j = 1; j < 4; j++) { a = fminf(a, wr_a[j]); b = fmaxf(b, wr_b[j]); }
        atomicExch(&ws[WS_PMIN + c * 4 + q], a);
        atomicExch(&ws[WS_PMAX + c * 4 + q], b);
        if (c == 0) {
            float ms  = wr_c[0] + wr_c[1] + wr_c[2] + wr_c[3];
            float ixn = fminf(fminf(wr_d[0], wr_d[1]), fminf(wr_d[2], wr_d[3]));
            float ixx = fmaxf(fmaxf(wr_e[0], wr_e[1]), fmaxf(wr_e[2], wr_e[3]));
            atomicExch(&ws[WS_MSUM + q], ms);
            atomicExch(&ws[WS_IPMN + q], ixn);
            atomicExch(&ws[WS_IPMX + q], ixx);
        }
    }
    gridbar();   // ---- barrier 1: min/max partials + zeroed cells visible ----

    // ---------------- phase B: histogram ----------------
    if (tid == 0) {
        float a = aldf(&ws[WS_PMIN + c * 4 + 0]);
        float b = aldf(&ws[WS_PMAX + c * 4 + 0]);
        #pragma unroll
        for (int j = 1; j < 4; j++) {
            a = fminf(a, aldf(&ws[WS_PMIN + c * 4 + j]));
            b = fmaxf(b, aldf(&ws[WS_PMAX + c * 4 + j]));
        }
        s_mn = a; s_mx = b;
    }
    hist[tid] = 0;
    __syncthreads();
    mn = s_mn; mx = s_mx;

    float w  = (mx - mn) * (1.0f / 256.0f);   // /256 exact, same as ref
    float sw = (w > 0.0f) ? w : 1.0f;

    int zc = 0;
    #pragma unroll
    for (int j = 0; j < 16; j++) {
        if (vm[j] == 0.0f) { zc++; }
        else {
            float bb = floorf((vm[j] - mn) / sw);
            bb = fminf(fmaxf(bb, 0.0f), 255.0f);
            atomicAdd(&hist[(int)bb], 1);
        }
    }
    #pragma unroll
    for (int s = 32; s > 0; s >>= 1) zc += __shfl_xor(zc, s, 64);
    if (lane == 0) wr_a[wave] = (float)zc;
    __syncthreads();
    if (tid == 0) {
        int z = (int)wr_a[0] + (int)wr_a[1] + (int)wr_a[2] + (int)wr_a[3];
        float bb = floorf((0.0f - mn) / sw);
        bb = fminf(fmaxf(bb, 0.0f), 255.0f);
        hist[(int)bb] += z;
    }
    __syncthreads();
    atomicAdd(&iws[WS_HIST + c * BINS + tid], hist[tid]);
    gridbar();   // ---- barrier 2: combined histograms visible ----

    // ---------------- phase C+D: scan, T LUT, remap, loss ----------------
    shc[tid] = aldi(&iws[WS_HIST + c * BINS + tid]);
    sh0[tid] = (c == 0) ? shc[tid] : aldi(&iws[WS_HIST + tid]);
    __syncthreads();
    if (wave < 2) {   // wave0: channel c cdf -> scdf; wave1: channel 0 cdf -> sc0
        const int* hsrc = wave ? sh0 : shc;
        float* dst = wave ? sc0 : scdf;
        int h0 = hsrc[4*lane], h1 = hsrc[4*lane+1], h2 = hsrc[4*lane+2], h3 = hsrc[4*lane+3];
        int p1 = h0 + h1, p2 = p1 + h2, s4 = p2 + h3;
        int sc = s4;
        #pragma unroll
        for (int off = 1; off < 64; off <<= 1) {
            int t = __shfl_up(sc, off, 64);
            if (lane >= off) sc += t;
        }
        int e = sc - s4;   // exclusive prefix; counts <=16384: float exact
        *(float4*)&dst[4*lane] = make_float4((float)(e + h0), (float)(e + p1),
                                             (float)(e + p2), (float)(e + s4));
    }
    if (tid == 128) {   // wave2 lane0: ch0 input stats, in parallel with scans
        float a = aldf(&ws[WS_IPMN + 0]);
        float b = aldf(&ws[WS_IPMX + 0]);
        #pragma unroll
        for (int j = 1; j < 4; j++) {
            a = fminf(a, aldf(&ws[WS_IPMN + j]));
            b = fmaxf(b, aldf(&ws[WS_IPMX + j]));
        }
        s_xmn = a; s_xmx = b;
    }
    __syncthreads();

    // T LUT from cdf0 + ch0 stats (identical math to the passing kernel)
    {
        float step = (s_xmx - s_xmn) * (1.0f / 256.0f);
        float rank = (float)(tid + 1);
        int idx = lbound(sc0, rank);
        float cp = (idx > 0) ? sc0[idx - 1] : 0.0f;
        float cc = sc0[idx];
        float ratio = fminf(fmaxf((rank - cp) / (1e-8f + cc), 0.0f), 1.0f);
        sT[tid] = s_xmn + (ratio + (float)idx) * step;
    }
    __syncthreads();

    float acc = 0.0f;
    int lo = lbound(scdf, (float)(base + 4 * tid + 1));   // then monotone march
    #pragma unroll
    for (int k = 0; k < 4; k++) {
        float rank0 = (float)(base + k * 1024 + 4 * tid + 1);
        #pragma unroll
        for (int j = 0; j < 4; j++) {
            float rnk = rank0 + (float)j;
            while (scdf[lo] < rnk) lo++;   // scdf[255]=N bounds the march
            float d = sT[lo] - vx[4 * k + j];
            acc += d * d;
        }
    }
    #pragma unroll
    for (int s = 32; s > 0; s >>= 1) acc += __shfl_xor(acc, s, 64);
    if (lane == 0) wr_b[wave] = acc;
    __syncthreads();

    if (tid == 0) {
        float ssum = wr_b[0] + wr_b[1] + wr_b[2] + wr_b[3];
        atomicAdd(&ws[WS_SSE], ssum);
        __threadfence();
        int old = atomicAdd(&iws[WS_CNT], 1);
        if (old == NBLK - 1) {   // last block: all sse adds visible
            float sse = aldf(&ws[WS_SSE]);
            float ms2 = aldf(&ws[WS_MSUM + 0]) + aldf(&ws[WS_MSUM + 1]) +
                        aldf(&ws[WS_MSUM + 2]) + aldf(&ws[WS_MSUM + 3]);
            double mean = (double)sse / (double)(C_CH * HW);
            out[0] = (float)(mean * (double)ms2 * (double)C_CH / (double)(C_CH * HW));
        }
    }
}

extern "C" void kernel_launch(void* const* d_in, const int* in_sizes, int n_in,
                              void* d_out, int out_size, void* d_ws, size_t ws_size,
                              hipStream_t stream) {
    const float* input = (const float*)d_in[0];
    const float* match = (const float*)d_in[1];
    const float* mask  = (const float*)d_in[2];
    float* ws          = (float*)d_ws;
    float* out         = (float*)d_out;

    fused<<<NBLK, 256, 0, stream>>>(input, match, mask, ws, out);
}

// Round 3
// 83.775 us; speedup vs baseline: 1.6986x; 1.6986x over previous
//
#include <hip/hip_runtime.h>
#include <math.h>

// Problem constants (fixed by setup_inputs): C=64, HW=128*128, bins=256.
#define C_CH  64
#define HW    16384
#define BINS  256
#define QHW   4096     // k0/k1: quarter channel per block
#define SEG   2048     // k2: segment per block
#define NB0   256
#define NB1   256
#define NB2   512

// ---- ws layout (32-bit cells). Cross-kernel via plain loads/stores:
// kernel-boundary coherence (proven in the passing 2-kernel version).
#define WS_H     0                       // 256 partial hists x 256 bins (int)
#define WS_PMIN  (NB1 * BINS)            // 256 floats: match*mask min, (c*4+q)
#define WS_PMAX  (WS_PMIN + 256)         // 256 floats: match*mask max
#define WS_IPMN  (WS_PMAX + 256)         // 4 floats: ch0 input*mask min partials
#define WS_IPMX  (WS_IPMN + 4)           // 4 floats: ch0 input*mask max partials
#define WS_MSUM  (WS_IPMX + 4)           // 4 floats: mask sum partials
#define WS_SSE   (WS_MSUM + 4)           // float SSE accumulator (zeroed by k0)
#define WS_CNT   (WS_SSE + 1)            // int ticket counter   (zeroed by k0)

__device__ inline float4 ld4(const float* p) { return *(const float4*)p; }
__device__ inline float aldf(float* p) { return atomicAdd(p, 0.0f); }

__device__ inline int lbound(const float* a, float rank) {
    int lo = 0, hi = BINS;
    while (lo < hi) { int mid = (lo + hi) >> 1; if (a[mid] < rank) lo = mid + 1; else hi = mid; }
    return (lo > 255) ? 255 : lo;   // defensive; a[255]=N>=rank
}

// k0: 256 blocks x 256 thr. Block (c=blk>>2,q=blk&3): min/max partials of
// match*mask over its quarter. c==0 blocks also: input*mask stats + mask sum
// partials. Block 0 zeroes SSE/ticket. All outputs plain stores.
__global__ __launch_bounds__(256) void k0_stats(const float* __restrict__ input,
                                                const float* __restrict__ match,
                                                const float* __restrict__ mask,
                                                float* __restrict__ ws) {
    const int blk = blockIdx.x, tid = threadIdx.x;
    const int c = blk >> 2, q = blk & 3;
    const int wave = tid >> 6, lane = tid & 63;
    __shared__ float wa[4], wb[4], wc[4], wd[4], we[4];

    const float* m  = match + c * HW + q * QHW;
    const float* mk = mask + q * QHW;

    float mn = INFINITY, mx = -INFINITY;
    float xmn = INFINITY, xmx = -INFINITY, ms = 0.0f;
    #pragma unroll
    for (int k = 0; k < 4; k++) {
        float4 mv = ld4(m  + k * 1024 + 4 * tid);
        float4 kv = ld4(mk + k * 1024 + 4 * tid);
        float a0 = mv.x * kv.x, a1 = mv.y * kv.y, a2 = mv.z * kv.z, a3 = mv.w * kv.w;
        mn = fminf(mn, fminf(fminf(a0, a1), fminf(a2, a3)));
        mx = fmaxf(mx, fmaxf(fmaxf(a0, a1), fmaxf(a2, a3)));
    }
    if (c == 0) {
        const float* x = input + q * QHW;
        #pragma unroll
        for (int k = 0; k < 4; k++) {
            float4 xv = ld4(x  + k * 1024 + 4 * tid);
            float4 kv = ld4(mk + k * 1024 + 4 * tid);   // L1-hot rereads
            float b0 = xv.x * kv.x, b1 = xv.y * kv.y, b2 = xv.z * kv.z, b3 = xv.w * kv.w;
            xmn = fminf(xmn, fminf(fminf(b0, b1), fminf(b2, b3)));
            xmx = fmaxf(xmx, fmaxf(fmaxf(b0, b1), fmaxf(b2, b3)));
            ms += kv.x + kv.y + kv.z + kv.w;   // 0/1 values: exact
        }
    }
    #pragma unroll
    for (int s = 32; s > 0; s >>= 1) {
        mn = fminf(mn, __shfl_xor(mn, s, 64));
        mx = fmaxf(mx, __shfl_xor(mx, s, 64));
        xmn = fminf(xmn, __shfl_xor(xmn, s, 64));
        xmx = fmaxf(xmx, __shfl_xor(xmx, s, 64));
        ms += __shfl_xor(ms, s, 64);
    }
    if (lane == 0) { wa[wave] = mn; wb[wave] = mx; wc[wave] = xmn; wd[wave] = xmx; we[wave] = ms; }
    __syncthreads();
    if (tid == 0) {
        float a = wa[0], b = wb[0], cmin = wc[0], cmax = wd[0], msum = we[0];
        #pragma unroll
        for (int j = 1; j < 4; j++) {
            a = fminf(a, wa[j]); b = fmaxf(b, wb[j]);
            cmin = fminf(cmin, wc[j]); cmax = fmaxf(cmax, wd[j]); msum += we[j];
        }
        ws[WS_PMIN + c * 4 + q] = a;
        ws[WS_PMAX + c * 4 + q] = b;
        if (c == 0) {
            ws[WS_IPMN + q] = cmin;
            ws[WS_IPMX + q] = cmax;
            ws[WS_MSUM + q] = msum;
            if (q == 0) { ws[WS_SSE] = 0.0f; ((int*)ws)[WS_CNT] = 0; }
        }
    }
}

// k1: 256 blocks x 256 thr, block (c,q): combine the 4 min/max partials,
// bin its 4096 values into a private LDS histogram (exact zeros counted
// without atomics), store the 256-bin PARTIAL hist with plain stores.
__global__ __launch_bounds__(256) void k1_hist(const float* __restrict__ match,
                                               const float* __restrict__ mask,
                                               float* __restrict__ ws) {
    const int blk = blockIdx.x, tid = threadIdx.x;
    const int c = blk >> 2, q = blk & 3;
    const int wave = tid >> 6, lane = tid & 63;
    __shared__ int hist[BINS];
    __shared__ float wz[4];

    // broadcast loads of the 4+4 partials (same addresses all threads: L1 hit)
    float mn = fminf(fminf(ws[WS_PMIN + c * 4 + 0], ws[WS_PMIN + c * 4 + 1]),
                     fminf(ws[WS_PMIN + c * 4 + 2], ws[WS_PMIN + c * 4 + 3]));
    float mx = fmaxf(fmaxf(ws[WS_PMAX + c * 4 + 0], ws[WS_PMAX + c * 4 + 1]),
                     fmaxf(ws[WS_PMAX + c * 4 + 2], ws[WS_PMAX + c * 4 + 3]));
    hist[tid] = 0;
    __syncthreads();

    // torch.histc: w = (mx-mn)/bins; safe_w = w>0 ? w : 1   (/256 exact)
    float w  = (mx - mn) * (1.0f / 256.0f);
    float sw = (w > 0.0f) ? w : 1.0f;

    const float* m  = match + c * HW + q * QHW;
    const float* mk = mask + q * QHW;

    int zc = 0;
    #pragma unroll
    for (int k = 0; k < 4; k++) {
        float4 mv = ld4(m  + k * 1024 + 4 * tid);
        float4 kv = ld4(mk + k * 1024 + 4 * tid);
        float v[4] = { mv.x * kv.x, mv.y * kv.y, mv.z * kv.z, mv.w * kv.w };
        #pragma unroll
        for (int j = 0; j < 4; j++) {
            if (v[j] == 0.0f) { zc++; }          // catches +0 and -0, as before
            else {
                float bb = floorf((v[j] - mn) / sw);
                bb = fminf(fmaxf(bb, 0.0f), 255.0f);   // clip in float like ref
                atomicAdd(&hist[(int)bb], 1);
            }
        }
    }
    #pragma unroll
    for (int s = 32; s > 0; s >>= 1) zc += __shfl_xor(zc, s, 64);
    if (lane == 0) wz[wave] = (float)zc;
    __syncthreads();
    if (tid == 0) {
        int z = (int)wz[0] + (int)wz[1] + (int)wz[2] + (int)wz[3];
        float bb = floorf((0.0f - mn) / sw);     // bin of v==0 (same calc)
        bb = fminf(fmaxf(bb, 0.0f), 255.0f);
        hist[(int)bb] += z;
    }
    __syncthreads();
    ((int*)ws)[WS_H + blk * BINS + tid] = hist[tid];   // partial hist, plain store
}

// k2: 512 blocks x 256 thr (8/channel, 2048 elems each -> 8 waves/CU).
// Sum 4 partial hists (c and ch0), dual wave scan, T LUT from ch0, then
// consecutive-8-ranks marching inversion (short, broadcast-friendly chain),
// block reduce -> atomicAdd(sse), ticket finale.
__global__ __launch_bounds__(256) void k2_loss(const float* __restrict__ input,
                                               const float* __restrict__ mask,
                                               float* __restrict__ ws,
                                               float* __restrict__ out) {
    const int blk = blockIdx.x, tid = threadIdx.x;
    const int c = blk >> 3, s = blk & 7, base = s * SEG;
    const int wave = tid >> 6, lane = tid & 63;
    int* iws = (int*)ws;

    __shared__ int   shc[BINS], sh0[BINS];
    __shared__ float scdf[BINS], sc0[BINS], sT[BINS], red[4];
    __shared__ float s_xmn, s_xmx;

    // combine partial hists: coalesced across the block (4 loads per table)
    {
        int h = iws[WS_H + (c * 4 + 0) * BINS + tid] + iws[WS_H + (c * 4 + 1) * BINS + tid]
              + iws[WS_H + (c * 4 + 2) * BINS + tid] + iws[WS_H + (c * 4 + 3) * BINS + tid];
        shc[tid] = h;
        sh0[tid] = (c == 0) ? h
                 : iws[WS_H + 0 * BINS + tid] + iws[WS_H + 1 * BINS + tid]
                 + iws[WS_H + 2 * BINS + tid] + iws[WS_H + 3 * BINS + tid];
    }
    if (tid == 0) {
        s_xmn = fminf(fminf(ws[WS_IPMN + 0], ws[WS_IPMN + 1]),
                      fminf(ws[WS_IPMN + 2], ws[WS_IPMN + 3]));
        s_xmx = fmaxf(fmaxf(ws[WS_IPMX + 0], ws[WS_IPMX + 1]),
                      fmaxf(ws[WS_IPMX + 2], ws[WS_IPMX + 3]));
    }
    __syncthreads();

    if (wave < 2) {   // wave0: channel c cdf; wave1: channel 0 cdf
        const int* hsrc = wave ? sh0 : shc;
        float* dst = wave ? sc0 : scdf;
        int h0 = hsrc[4*lane], h1 = hsrc[4*lane+1], h2 = hsrc[4*lane+2], h3 = hsrc[4*lane+3];
        int p1 = h0 + h1, p2 = p1 + h2, s4 = p2 + h3;
        int sc = s4;
        #pragma unroll
        for (int off = 1; off < 64; off <<= 1) {
            int t = __shfl_up(sc, off, 64);
            if (lane >= off) sc += t;
        }
        int e = sc - s4;   // exclusive prefix; counts <=16384: float exact
        *(float4*)&dst[4*lane] = make_float4((float)(e + h0), (float)(e + p1),
                                             (float)(e + p2), (float)(e + s4));
    }
    __syncthreads();

    // T LUT from cdf0 + ch0 stats (identical math to the passing kernel)
    {
        float step = (s_xmx - s_xmn) * (1.0f / 256.0f);
        float rank = (float)(tid + 1);
        int idx = lbound(sc0, rank);
        float cp = (idx > 0) ? sc0[idx - 1] : 0.0f;
        float cc = sc0[idx];
        float ratio = fminf(fmaxf((rank - cp) / (1e-8f + cc), 0.0f), 1.0f);
        sT[tid] = s_xmn + (ratio + (float)idx) * step;
    }
    __syncthreads();

    const float* x  = input + c * HW + base;
    const float* mk = mask + base;

    float acc = 0.0f;
    const int r0 = base + 8 * tid + 1;        // consecutive ranks per thread
    int lo = lbound(scdf, (float)r0);
    #pragma unroll
    for (int k = 0; k < 2; k++) {
        float4 xv = ld4(x  + 8 * tid + 4 * k);
        float4 kv = ld4(mk + 8 * tid + 4 * k);
        float v[4] = { xv.x * kv.x, xv.y * kv.y, xv.z * kv.z, xv.w * kv.w };
        #pragma unroll
        for (int j = 0; j < 4; j++) {
            float rnk = (float)(r0 + 4 * k + j);
            while (scdf[lo] < rnk) lo++;      // short march: ~1-2 bins/thread
            float d = sT[lo] - v[j];
            acc += d * d;
        }
    }
    #pragma unroll
    for (int s2 = 32; s2 > 0; s2 >>= 1) acc += __shfl_xor(acc, s2, 64);
    if (lane == 0) red[wave] = acc;
    __syncthreads();

    if (tid == 0) {
        float ssum = red[0] + red[1] + red[2] + red[3];
        atomicAdd(&ws[WS_SSE], ssum);
        __threadfence();
        int old = atomicAdd(&iws[WS_CNT], 1);
        if (old == NB2 - 1) {                 // last block: all sse adds visible
            float sse = aldf(&ws[WS_SSE]);
            float ms2 = ws[WS_MSUM + 0] + ws[WS_MSUM + 1] + ws[WS_MSUM + 2] + ws[WS_MSUM + 3];
            double mean = (double)sse / (double)(C_CH * HW);
            out[0] = (float)(mean * (double)ms2 * (double)C_CH / (double)(C_CH * HW));
        }
    }
}

extern "C" void kernel_launch(void* const* d_in, const int* in_sizes, int n_in,
                              void* d_out, int out_size, void* d_ws, size_t ws_size,
                              hipStream_t stream) {
    const float* input = (const float*)d_in[0];
    const float* match = (const float*)d_in[1];
    const float* mask  = (const float*)d_in[2];
    float* ws          = (float*)d_ws;
    float* out         = (float*)d_out;

    k0_stats<<<NB0, 256, 0, stream>>>(input, match, mask, ws);
    k1_hist<<<NB1, 256, 0, stream>>>(match, mask, ws);
    k2_loss<<<NB2, 256, 0, stream>>>(input, mask, ws, out);
}